// Round 4
// baseline (274.488 us; speedup 1.0000x reference)
//
#include <hip/hip_runtime.h>
#include <hip/hip_bf16.h>

typedef __hip_bfloat16 bf16;
typedef unsigned int uint;
typedef unsigned short ushort;

using frag8 = __attribute__((ext_vector_type(8))) short;   // 8 bf16
using f32x4 = __attribute__((ext_vector_type(4))) float;

#define HWH 784     // 28*28
#define PPITCH 30   // padded plane pitch (shorts)
#define PPLANE 900  // 30*30 shorts per plane
#define PBLK 10800  // 12*900 shorts per (b,g)

// ---------------------------------------------------------------------------
// Fold fc_w (9x12) into dep_w (256,9,3,3):  W2[oc][c12][k9]; also biascat.
// ---------------------------------------------------------------------------
__global__ __launch_bounds__(256) void fold_w2(const float* __restrict__ fc_w,
                                               const float* __restrict__ dep_w,
                                               const float* __restrict__ b1,
                                               const float* __restrict__ b2,
                                               const float* __restrict__ b3,
                                               float* __restrict__ W2,
                                               float* __restrict__ biascat) {
    int idx = blockIdx.x * 256 + threadIdx.x;   // oc*108 + c12*9 + k9
    if (idx < 768) {
        const float* bs = idx < 256 ? b1 : (idx < 512 ? b2 : b3);
        biascat[idx] = bs[idx & 255];
    }
    if (idx >= 256 * 108) return;
    int oc  = idx / 108;
    int r   = idx % 108;
    int c12 = r / 9;
    int k9  = r % 9;
    float s = 0.f;
#pragma unroll
    for (int o = 0; o < 9; ++o)
        s += fc_w[o * 12 + c12] * dep_w[oc * 81 + o * 9 + k9];
    W2[idx] = s;
}

// ---------------------------------------------------------------------------
// Weights f32 -> bf16, concatenated [768][256] (q:w1, k:w2, v:w3)
// ---------------------------------------------------------------------------
__global__ __launch_bounds__(256) void wprep(const float* __restrict__ w1,
                                             const float* __restrict__ w2,
                                             const float* __restrict__ w3,
                                             bf16* __restrict__ wbf) {
    int row = blockIdx.x, tid = threadIdx.x;
    const float* src = row < 256 ? w1 : (row < 512 ? w2 : w3);
    wbf[row * 256 + tid] = __float2bfloat16(src[(row & 255) * 256 + tid]);
}

// ---------------------------------------------------------------------------
// x [b][c=256][n=784] f32  ->  xT [b][n=784][c=256] bf16  (32x32 LDS tiles)
// ---------------------------------------------------------------------------
__global__ __launch_bounds__(256) void xpose(const float* __restrict__ x,
                                             bf16* __restrict__ xT) {
    __shared__ float t[32][33];
    const int n0 = blockIdx.x * 32, c0 = blockIdx.y * 32, b = blockIdx.z;
    const int tid = threadIdx.x;
    const float* xb = x + (size_t)b * (256 * HWH);
#pragma unroll
    for (int e = tid; e < 1024; e += 256) {
        int r = e >> 5, col = e & 31;           // r: c-index, col: n-index
        int n = n0 + col;
        t[r][col] = (n < HWH) ? xb[(size_t)(c0 + r) * HWH + n] : 0.f;
    }
    __syncthreads();
#pragma unroll
    for (int e = tid; e < 512; e += 256) {
        int r = e >> 4, cp = (e & 15) * 2;      // r: n-index, cp: c-pair
        int n = n0 + r;
        if (n < HWH) {
            __hip_bfloat162 h;
            h.x = __float2bfloat16(t[cp][r]);
            h.y = __float2bfloat16(t[cp + 1][r]);
            *reinterpret_cast<__hip_bfloat162*>(
                &xT[((size_t)b * HWH + n) * 256 + c0 + cp]) = h;
        }
    }
}

// ---------------------------------------------------------------------------
// MFMA GEMM (R3 restructure): grid (13 n-tiles x 64 b). Each block stages its
// FULL B panel (n=64, K=256 -> 32 KB) into LDS once, syncs ONCE, then loops
// the 6 m-tiles with ZERO further barriers. A fragments stream global->VGPR
// (wbf = 393 KB, L2-resident; per-wave m-quarter => A read exactly once per
// block). Old structure paid 2 barriers + vmcnt(0) drain per K-step at 11%
// MfmaUtil / 25% occupancy (latency-bound, 72 us).
// perm output: PADDED planes, image (y,x) at (y+1)*30+x+1; borders garbage.
// m -> sec=m/256, ch=m%256, g=ch%64, head=ch/64, t=sec*4+head.
// ---------------------------------------------------------------------------
__device__ inline void load_lds16(const bf16* g, short* lds) {
    __builtin_amdgcn_global_load_lds(
        (const __attribute__((address_space(1))) void*)g,
        (__attribute__((address_space(3))) void*)lds, 16, 0, 0);
}

__global__ __launch_bounds__(256) void gemm_mfma(const bf16* __restrict__ wbf,
                                                 const float* __restrict__ biascat,
                                                 const bf16* __restrict__ xT,
                                                 bf16* __restrict__ perm) {
    __shared__ short ldsB[16384];               // 32 KB: [kc 0..7][jb 0..3][512]

    const int tid  = threadIdx.x;
    const int wave = tid >> 6, lane = tid & 63;
    const int b    = blockIdx.y;
    const int n0   = blockIdx.x * 64;
    const int lrow = lane & 15, lkc = lane >> 4;  // fragment row / k-chunk

    const bf16* xb = xT + (size_t)b * (HWH * 256);

    // ---- stage full B panel: 32 slots of 1024 B; wave w stages slots 8w..8w+7
#pragma unroll
    for (int si = 0; si < 8; ++si) {
        const int s = wave * 8 + si;
        const int kc = s >> 2, jb = s & 3;
        int n = n0 + jb * 16 + lrow;
        if (n > HWH - 1) n = HWH - 1;           // clamp: OOB cols never stored
        const bf16* gb = xb + (size_t)n * 256 + kc * 32 + lkc * 8;
        load_lds16(gb, &ldsB[s * 512]);
    }
    __syncthreads();                            // the ONLY barrier

    // ---- m-loop: 6 tiles of 128 rows; wave owns a 32-row quarter ----
#pragma unroll 1   // keep register pressure bounded (R2 lesson)
    for (int mt = 0; mt < 6; ++mt) {
        f32x4 acc[2][4] = {};
        const int rowbase = mt * 128 + wave * 32 + lrow;
#pragma unroll 2
        for (int kc = 0; kc < 8; ++kc) {
            frag8 a[2], bb[4];
#pragma unroll
            for (int i = 0; i < 2; ++i)
                a[i] = *reinterpret_cast<const frag8*>(
                    &wbf[(size_t)(rowbase + i * 16) * 256 + kc * 32 + lkc * 8]);
#pragma unroll
            for (int j = 0; j < 4; ++j)
                bb[j] = *reinterpret_cast<const frag8*>(
                    &ldsB[(kc * 4 + j) * 512 + lane * 8]);
#pragma unroll
            for (int i = 0; i < 2; ++i)
#pragma unroll
                for (int j = 0; j < 4; ++j)
                    acc[i][j] = __builtin_amdgcn_mfma_f32_16x16x32_bf16(
                        a[i], bb[j], acc[i][j], 0, 0, 0);
        }

        // Epilogue: C/D layout col=lane&15 (n), row=(lane>>4)*4+reg (m)
        // padded plane position (y+1)*30 + (x+1) = col + 2*(col/28) + 31
#pragma unroll
        for (int i = 0; i < 2; ++i) {
            const int rowb = mt * 128 + wave * 32 + i * 16 + lkc * 4;
            bf16* base[4]; float bias4[4];
#pragma unroll
            for (int r = 0; r < 4; ++r) {
                const int m = rowb + r;
                const int sec = m >> 8, ch = m & 255;
                base[r] = perm + ((size_t)b * 64 + (ch & 63)) * PBLK
                               + (size_t)(sec * 4 + (ch >> 6)) * PPLANE;
                bias4[r] = biascat[m];
            }
#pragma unroll
            for (int j = 0; j < 4; ++j) {
                const int col = n0 + j * 16 + lrow;
                if (col < HWH) {
                    const int pos = col + 2 * (col / 28) + 31;
#pragma unroll
                    for (int r = 0; r < 4; ++r)
                        base[r][pos] = __float2bfloat16(acc[i][j][r] + bias4[r]);
                }
            }
        }
    }
}

// ---------------------------------------------------------------------------
// attmean: interior 12x12 window means of v, prescaled by rate1/144.
// attm[b][c][25] f32. One wave per channel; lanes 0..27 own columns.
// v channel c lives at perm[b][c&63][8 + c/64] (bias already included).
// ---------------------------------------------------------------------------
__global__ __launch_bounds__(256) void attmean(const bf16* __restrict__ perm,
                                               const float* __restrict__ rate1,
                                               float* __restrict__ attm) {
    const int b = blockIdx.y, cg = blockIdx.x;            // cg in [0,64)
    const int wave = threadIdx.x >> 6, lane = threadIdx.x & 63;
    const int c = cg * 4 + wave;                          // channel 0..255
    const bf16* vp = perm + ((size_t)(b * 64 + (c & 63)) * 12 + 8 + (c >> 6)) * (size_t)PPLANE;

    float cs[5] = {0.f, 0.f, 0.f, 0.f, 0.f};              // per-wi column sums
    if (lane < 28) {
#pragma unroll
        for (int y = 0; y < 28; ++y) {
            float v = __bfloat162float(vp[(y + 1) * PPITCH + lane + 1]);
#pragma unroll
            for (int wi = 0; wi < 5; ++wi)
                if (y >= 4 * wi && y <= 4 * wi + 11) cs[wi] += v;
        }
    }
    const float r1s = rate1[0] * (1.0f / 144.0f);
#pragma unroll
    for (int wi = 0; wi < 5; ++wi) {
        float p = cs[wi];
#pragma unroll
        for (int d = 1; d < 32; d <<= 1) {                // inclusive prefix over lanes
            float t = __shfl_up(p, d);
            if (lane >= d) p += t;
        }
        float hi = __shfl(p, 4 * lane + 11);              // valid for lane<5
        float lo = __shfl(p, 4 * lane - 1);
        if (lane < 5) {
            float w = hi - (lane ? lo : 0.f);
            attm[((size_t)b * 256 + c) * 25 + wi * 5 + lane] = w * r1s;
        }
    }
}

// ---------------------------------------------------------------------------
// out_fused5: out = att(precomputed means) + rate2 * conv.
// Phase A: straight uint4 copy of 12 padded planes (21.6 KB) + weights + att.
// Phase A2: zero halo borders in LDS (116 shorts/plane).
// Phase C: 3x3 conv, 196 threads x 4 oc x 4 px, pitch 30 (bank stride 15).
// LDS ~24.3 KB -> 6 blocks/CU by LDS.
// VGPR history: (256,6) clamp -> 40 VGPR, spill catastrophe (R1).
//               plain bounds + full c-unroll -> 256 VGPR, compiler hoisted
//               12 channels of rr loads (~216 live floats), spilled anyway (R2).
// Fix: #pragma unroll 1 on the channel loop — bounds live set to ~60 floats
// (one channel's rr[3][6] + acc[4][4] + transient wk). DO NOT re-unroll.
// ---------------------------------------------------------------------------
__global__ __launch_bounds__(256) void out_fused5(
    const bf16* __restrict__ perm, const float* __restrict__ W2,
    const float* __restrict__ attm, const float* __restrict__ rate2,
    float* __restrict__ out) {
    __shared__ __align__(16) short planes[12 * PPLANE];   // 21600 B, linear
    __shared__ float w2s[4][12][12];                      // [oc][c][k], k 9->12
    __shared__ float attbs[4][25];

    const int g = blockIdx.x, b = blockIdx.y, tid = threadIdx.x;

    // ---- phase A: linear LDS fill ----
    const uint4* src = (const uint4*)(perm + (size_t)(b * 64 + g) * PBLK);
#pragma unroll
    for (int it = 0; it < 6; ++it) {
        int e = tid + it * 256;                 // 1350 x 16B chunks
        if (e < 1350) ((uint4*)planes)[e] = src[e];
    }
    for (int e = tid; e < 576; e += 256) {
        int oc = e / 144, rem = e % 144, cc = rem / 12, k = rem % 12;
        w2s[oc][cc][k] = (k < 9) ? W2[(4 * g + oc) * 108 + cc * 9 + k] : 0.f;
    }
    if (tid < 100)
        attbs[tid / 25][tid % 25] =
            attm[((size_t)b * 256 + 4 * g + tid / 25) * 25 + tid % 25];
    __syncthreads();

    // ---- phase A2: zero halo borders (global borders hold garbage) ----
    for (int e = tid; e < 1392; e += 256) {
        int c12 = e / 116, u = e % 116, idx;
        if (u < 30)      idx = u;                         // top row
        else if (u < 60) idx = 870 + (u - 30);            // bottom row
        else { int v = u - 60; idx = ((v >> 1) + 1) * PPITCH + (v & 1) * 29; }
        planes[c12 * PPLANE + idx] = 0;
    }
    __syncthreads();

    // ---- phase C: conv. Lanes consecutive in y; bank stride 15 (odd). ----
    float acc[4][4] = {};   // [oc][px]
    const int y = tid % 28, xs = tid / 28, x0 = xs * 4;
    if (tid < 196) {
#pragma unroll 1   // CRITICAL: full unroll makes the scheduler hoist all 12
                   // channels' plane loads (~216 live floats) -> 256 VGPR + spill
        for (int c = 0; c < 12; ++c) {
            float rr[3][6];
#pragma unroll
            for (int dy = 0; dy < 3; ++dy) {
                const uint* row = (const uint*)&planes[c * PPLANE + (y + dy) * PPITCH + x0];
#pragma unroll
                for (int jp = 0; jp < 3; ++jp) {
                    uint w = row[jp];
                    float2 f = __bfloat1622float2(*(const __hip_bfloat162*)&w);
                    rr[dy][2 * jp]     = f.x;
                    rr[dy][2 * jp + 1] = f.y;
                }
            }
#pragma unroll
            for (int oc = 0; oc < 4; ++oc) {
                const float4* wr = reinterpret_cast<const float4*>(&w2s[oc][c][0]);
                float4 wa = wr[0], wb = wr[1], wc = wr[2];
                const float wk[9] = {wa.x, wa.y, wa.z, wa.w, wb.x, wb.y, wb.z, wb.w, wc.x};
#pragma unroll
                for (int ky = 0; ky < 3; ++ky)
#pragma unroll
                    for (int kx = 0; kx < 3; ++kx) {
                        float wv = wk[ky * 3 + kx];
#pragma unroll
                        for (int px = 0; px < 4; ++px)
                            acc[oc][px] += wv * rr[ky][px + kx];
                    }
            }
        }

        // ---- phase D: combine + store (att values ready since phase A) ----
        const float r2 = rate2[0];
        const int wi = (y >> 2) - 1, wj = xs - 1;
        const bool inter = (wi >= 0) & (wi < 5) & (wj >= 0) & (wj < 5);
#pragma unroll
        for (int oc = 0; oc < 4; ++oc) {
            float av = inter ? attbs[oc][wi * 5 + wj] : 0.f;
            float4 o;
            o.x = av + r2 * acc[oc][0];
            o.y = av + r2 * acc[oc][1];
            o.z = av + r2 * acc[oc][2];
            o.w = av + r2 * acc[oc][3];
            *reinterpret_cast<float4*>(
                &out[((size_t)(b * 256 + 4 * g + oc)) * HWH + y * 28 + x0]) = o;
        }
    }
}

// ---------------------------------------------------------------------------
extern "C" void kernel_launch(void* const* d_in, const int* in_sizes, int n_in,
                              void* d_out, int out_size, void* d_ws, size_t ws_size,
                              hipStream_t stream) {
    const float* x     = (const float*)d_in[0];
    const float* w1    = (const float*)d_in[1];
    const float* b1    = (const float*)d_in[2];
    const float* w2    = (const float*)d_in[3];
    const float* b2    = (const float*)d_in[4];
    const float* w3    = (const float*)d_in[5];
    const float* b3    = (const float*)d_in[6];
    const float* fc_w  = (const float*)d_in[7];
    const float* dep_w = (const float*)d_in[8];
    // d_in[9]/d_in[10] = rel_height/rel_width: provably dead (mask collapse)
    const float* rate1 = (const float*)d_in[11];
    const float* rate2 = (const float*)d_in[12];
    float* out = (float*)d_out;

    // workspace layout (bytes):
    //   perm    [0, 88473600)          64*64*12*900*2 (PADDED planes)
    //   xT      [88473600, 114163712)  64*784*256*2
    //   attm    = xT base (reused AFTER gemm consumes xT; stream-ordered)
    //   wbf     [114163712, 114556928) 768*256*2
    //   W2      [114556928, 114667520) 256*108*4
    //   biascat [114667520, 114670592) 768*4
    char* wsb = (char*)d_ws;
    bf16*  perm    = (bf16*)wsb;
    bf16*  xT      = (bf16*)(wsb + 88473600);
    float* attm    = (float*)(wsb + 88473600);           // alias of xT
    bf16*  wbf     = (bf16*)(wsb + 114163712);
    float* W2      = (float*)(wsb + 114556928);
    float* biascat = (float*)(wsb + 114667520);

    fold_w2   <<<dim3(108),        dim3(256), 0, stream>>>(fc_w, dep_w, b1, b2, b3, W2, biascat);
    wprep     <<<dim3(768),        dim3(256), 0, stream>>>(w1, w2, w3, wbf);
    xpose     <<<dim3(25, 8, 64),  dim3(256), 0, stream>>>(x, xT);
    gemm_mfma <<<dim3(13, 64),     dim3(256), 0, stream>>>(wbf, biascat, xT, perm);
    attmean   <<<dim3(64, 64),     dim3(256), 0, stream>>>(perm, rate1, attm);
    out_fused5<<<dim3(64, 64),     dim3(256), 0, stream>>>(perm, W2, attm, rate2, out);
}

// Round 5
// 264.485 us; speedup vs baseline: 1.0378x; 1.0378x over previous
//
#include <hip/hip_runtime.h>
#include <hip/hip_bf16.h>

typedef __hip_bfloat16 bf16;
typedef unsigned int uint;
typedef unsigned short ushort;

using frag8 = __attribute__((ext_vector_type(8))) short;   // 8 bf16
using f32x4 = __attribute__((ext_vector_type(4))) float;

#define HWH 784     // 28*28
#define PPITCH 30   // padded plane pitch (shorts)
#define PPLANE 900  // 30*30 shorts per plane
#define PBLK 10800  // 12*900 shorts per (b,g)

// ---------------------------------------------------------------------------
// Fold fc_w (9x12) into dep_w (256,9,3,3):  W2[oc][c12][k9]; also biascat.
// ---------------------------------------------------------------------------
__global__ __launch_bounds__(256) void fold_w2(const float* __restrict__ fc_w,
                                               const float* __restrict__ dep_w,
                                               const float* __restrict__ b1,
                                               const float* __restrict__ b2,
                                               const float* __restrict__ b3,
                                               float* __restrict__ W2,
                                               float* __restrict__ biascat) {
    int idx = blockIdx.x * 256 + threadIdx.x;   // oc*108 + c12*9 + k9
    if (idx < 768) {
        const float* bs = idx < 256 ? b1 : (idx < 512 ? b2 : b3);
        biascat[idx] = bs[idx & 255];
    }
    if (idx >= 256 * 108) return;
    int oc  = idx / 108;
    int r   = idx % 108;
    int c12 = r / 9;
    int k9  = r % 9;
    float s = 0.f;
#pragma unroll
    for (int o = 0; o < 9; ++o)
        s += fc_w[o * 12 + c12] * dep_w[oc * 81 + o * 9 + k9];
    W2[idx] = s;
}

// ---------------------------------------------------------------------------
// Weights f32 -> bf16, concatenated [768][256] (q:w1, k:w2, v:w3)
// ---------------------------------------------------------------------------
__global__ __launch_bounds__(256) void wprep(const float* __restrict__ w1,
                                             const float* __restrict__ w2,
                                             const float* __restrict__ w3,
                                             bf16* __restrict__ wbf) {
    int row = blockIdx.x, tid = threadIdx.x;
    const float* src = row < 256 ? w1 : (row < 512 ? w2 : w3);
    wbf[row * 256 + tid] = __float2bfloat16(src[(row & 255) * 256 + tid]);
}

// ---------------------------------------------------------------------------
// x [b][c=256][n=784] f32  ->  xT [b][n=784][c=256] bf16  (32x32 LDS tiles)
// ---------------------------------------------------------------------------
__global__ __launch_bounds__(256) void xpose(const float* __restrict__ x,
                                             bf16* __restrict__ xT) {
    __shared__ float t[32][33];
    const int n0 = blockIdx.x * 32, c0 = blockIdx.y * 32, b = blockIdx.z;
    const int tid = threadIdx.x;
    const float* xb = x + (size_t)b * (256 * HWH);
#pragma unroll
    for (int e = tid; e < 1024; e += 256) {
        int r = e >> 5, col = e & 31;           // r: c-index, col: n-index
        int n = n0 + col;
        t[r][col] = (n < HWH) ? xb[(size_t)(c0 + r) * HWH + n] : 0.f;
    }
    __syncthreads();
#pragma unroll
    for (int e = tid; e < 512; e += 256) {
        int r = e >> 4, cp = (e & 15) * 2;      // r: n-index, cp: c-pair
        int n = n0 + r;
        if (n < HWH) {
            __hip_bfloat162 h;
            h.x = __float2bfloat16(t[cp][r]);
            h.y = __float2bfloat16(t[cp + 1][r]);
            *reinterpret_cast<__hip_bfloat162*>(
                &xT[((size_t)b * HWH + n) * 256 + c0 + cp]) = h;
        }
    }
}

// ---------------------------------------------------------------------------
// MFMA GEMM (R5): grid (13 n-tiles x 3 m-chunks x 64 b) = 2496 blocks.
// Each block stages its FULL B panel (n=64, K=256 -> 32 KB) into LDS once,
// syncs ONCE, then computes 2 m-tiles (256 rows) with zero further barriers.
// A fragments stream global->VGPR with distance-1 prefetch (wbf = 393 KB,
// L2-resident). History: R4's 6-m-tiles/block version (832 blocks) was
// latency-bound at 3.25 blocks/CU (MfmaUtil 9%, occ 22%, 86 us) — balance
// and co-residency matter more than B-refetch (R4 proved fetch is cheap).
// perm output: PADDED planes, image (y,x) at (y+1)*30+x+1; borders garbage.
// m -> sec=m/256, ch=m%256, g=ch%64, head=ch/64, t=sec*4+head.
// ---------------------------------------------------------------------------
__device__ inline void load_lds16(const bf16* g, short* lds) {
    __builtin_amdgcn_global_load_lds(
        (const __attribute__((address_space(1))) void*)g,
        (__attribute__((address_space(3))) void*)lds, 16, 0, 0);
}

__global__ __launch_bounds__(256) void gemm_mfma(const bf16* __restrict__ wbf,
                                                 const float* __restrict__ biascat,
                                                 const bf16* __restrict__ xT,
                                                 bf16* __restrict__ perm) {
    __shared__ short ldsB[16384];               // 32 KB: [kc 0..7][jb 0..3][512]

    const int tid  = threadIdx.x;
    const int wave = tid >> 6, lane = tid & 63;
    const int b    = blockIdx.z;
    const int mc   = blockIdx.y;                // m-chunk: 2 m-tiles each
    const int n0   = blockIdx.x * 64;
    const int lrow = lane & 15, lkc = lane >> 4;  // fragment row / k-chunk

    const bf16* xb = xT + (size_t)b * (HWH * 256);

    // ---- stage full B panel: 32 slots of 1024 B; wave w stages slots 8w..8w+7
#pragma unroll
    for (int si = 0; si < 8; ++si) {
        const int s = wave * 8 + si;
        const int kc = s >> 2, jb = s & 3;
        int n = n0 + jb * 16 + lrow;
        if (n > HWH - 1) n = HWH - 1;           // clamp: OOB cols never stored
        const bf16* gb = xb + (size_t)n * 256 + kc * 32 + lkc * 8;
        load_lds16(gb, &ldsB[s * 512]);
    }
    __syncthreads();                            // the ONLY barrier

    // ---- 2 m-tiles of 128 rows; wave owns a 32-row quarter of each ----
#pragma unroll 1   // keep register pressure bounded (R2 lesson)
    for (int mti = 0; mti < 2; ++mti) {
        const int mt = mc * 2 + mti;
        f32x4 acc[2][4] = {};
        const int rowbase = mt * 128 + wave * 32 + lrow;
        const bf16* aptr = wbf + (size_t)rowbase * 256 + lkc * 8;

        // distance-1 A prefetch: MFMA never waits on its own A-load
        frag8 a0 = *reinterpret_cast<const frag8*>(&aptr[0]);
        frag8 a1 = *reinterpret_cast<const frag8*>(&aptr[16 * 256]);
#pragma unroll 2
        for (int kc = 0; kc < 8; ++kc) {
            const frag8 ac0 = a0, ac1 = a1;
            if (kc < 7) {
                a0 = *reinterpret_cast<const frag8*>(&aptr[(kc + 1) * 32]);
                a1 = *reinterpret_cast<const frag8*>(&aptr[16 * 256 + (kc + 1) * 32]);
            }
            frag8 bb[4];
#pragma unroll
            for (int j = 0; j < 4; ++j)
                bb[j] = *reinterpret_cast<const frag8*>(
                    &ldsB[(kc * 4 + j) * 512 + lane * 8]);
#pragma unroll
            for (int j = 0; j < 4; ++j) {
                acc[0][j] = __builtin_amdgcn_mfma_f32_16x16x32_bf16(
                    ac0, bb[j], acc[0][j], 0, 0, 0);
                acc[1][j] = __builtin_amdgcn_mfma_f32_16x16x32_bf16(
                    ac1, bb[j], acc[1][j], 0, 0, 0);
            }
        }

        // Epilogue: C/D layout col=lane&15 (n), row=(lane>>4)*4+reg (m)
        // padded plane position (y+1)*30 + (x+1) = col + 2*(col/28) + 31
#pragma unroll
        for (int i = 0; i < 2; ++i) {
            const int rowb = mt * 128 + wave * 32 + i * 16 + lkc * 4;
            bf16* base[4]; float bias4[4];
#pragma unroll
            for (int r = 0; r < 4; ++r) {
                const int m = rowb + r;
                const int sec = m >> 8, ch = m & 255;
                base[r] = perm + ((size_t)b * 64 + (ch & 63)) * PBLK
                               + (size_t)(sec * 4 + (ch >> 6)) * PPLANE;
                bias4[r] = biascat[m];
            }
#pragma unroll
            for (int j = 0; j < 4; ++j) {
                const int col = n0 + j * 16 + lrow;
                if (col < HWH) {
                    const int pos = col + 2 * (col / 28) + 31;
#pragma unroll
                    for (int r = 0; r < 4; ++r)
                        base[r][pos] = __float2bfloat16(acc[i][j][r] + bias4[r]);
                }
            }
        }
    }
}

// ---------------------------------------------------------------------------
// attmean: interior 12x12 window means of v, prescaled by rate1/144.
// attm[b][c][25] f32. One wave per channel; lanes 0..27 own columns.
// v channel c lives at perm[b][c&63][8 + c/64] (bias already included).
// ---------------------------------------------------------------------------
__global__ __launch_bounds__(256) void attmean(const bf16* __restrict__ perm,
                                               const float* __restrict__ rate1,
                                               float* __restrict__ attm) {
    const int b = blockIdx.y, cg = blockIdx.x;            // cg in [0,64)
    const int wave = threadIdx.x >> 6, lane = threadIdx.x & 63;
    const int c = cg * 4 + wave;                          // channel 0..255
    const bf16* vp = perm + ((size_t)(b * 64 + (c & 63)) * 12 + 8 + (c >> 6)) * (size_t)PPLANE;

    float cs[5] = {0.f, 0.f, 0.f, 0.f, 0.f};              // per-wi column sums
    if (lane < 28) {
#pragma unroll
        for (int y = 0; y < 28; ++y) {
            float v = __bfloat162float(vp[(y + 1) * PPITCH + lane + 1]);
#pragma unroll
            for (int wi = 0; wi < 5; ++wi)
                if (y >= 4 * wi && y <= 4 * wi + 11) cs[wi] += v;
        }
    }
    const float r1s = rate1[0] * (1.0f / 144.0f);
#pragma unroll
    for (int wi = 0; wi < 5; ++wi) {
        float p = cs[wi];
#pragma unroll
        for (int d = 1; d < 32; d <<= 1) {                // inclusive prefix over lanes
            float t = __shfl_up(p, d);
            if (lane >= d) p += t;
        }
        float hi = __shfl(p, 4 * lane + 11);              // valid for lane<5
        float lo = __shfl(p, 4 * lane - 1);
        if (lane < 5) {
            float w = hi - (lane ? lo : 0.f);
            attm[((size_t)b * 256 + c) * 25 + wi * 5 + lane] = w * r1s;
        }
    }
}

// ---------------------------------------------------------------------------
// out_fused5: out = att(precomputed means) + rate2 * conv.
// Phase A: straight uint4 copy of 12 padded planes (21.6 KB) + weights + att.
// Phase A2: zero halo borders in LDS (116 shorts/plane).
// Phase C: 3x3 conv, 196 threads x 4 oc x 4 px, pitch 30 (bank stride 15).
// LDS ~24.3 KB -> 6 blocks/CU by LDS.
// VGPR history: (256,6) clamp -> 40 VGPR, spill catastrophe (R1).
//               plain bounds + full c-unroll -> 256 VGPR, compiler hoisted
//               12 channels of rr loads (~216 live floats), spilled anyway (R2).
// Fix: #pragma unroll 1 on the channel loop — bounds live set to ~60 floats
// (one channel's rr[3][6] + acc[4][4] + transient wk). DO NOT re-unroll.
// ---------------------------------------------------------------------------
__global__ __launch_bounds__(256) void out_fused5(
    const bf16* __restrict__ perm, const float* __restrict__ W2,
    const float* __restrict__ attm, const float* __restrict__ rate2,
    float* __restrict__ out) {
    __shared__ __align__(16) short planes[12 * PPLANE];   // 21600 B, linear
    __shared__ float w2s[4][12][12];                      // [oc][c][k], k 9->12
    __shared__ float attbs[4][25];

    const int g = blockIdx.x, b = blockIdx.y, tid = threadIdx.x;

    // ---- phase A: linear LDS fill ----
    const uint4* src = (const uint4*)(perm + (size_t)(b * 64 + g) * PBLK);
#pragma unroll
    for (int it = 0; it < 6; ++it) {
        int e = tid + it * 256;                 // 1350 x 16B chunks
        if (e < 1350) ((uint4*)planes)[e] = src[e];
    }
    for (int e = tid; e < 576; e += 256) {
        int oc = e / 144, rem = e % 144, cc = rem / 12, k = rem % 12;
        w2s[oc][cc][k] = (k < 9) ? W2[(4 * g + oc) * 108 + cc * 9 + k] : 0.f;
    }
    if (tid < 100)
        attbs[tid / 25][tid % 25] =
            attm[((size_t)b * 256 + 4 * g + tid / 25) * 25 + tid % 25];
    __syncthreads();

    // ---- phase A2: zero halo borders (global borders hold garbage) ----
    for (int e = tid; e < 1392; e += 256) {
        int c12 = e / 116, u = e % 116, idx;
        if (u < 30)      idx = u;                         // top row
        else if (u < 60) idx = 870 + (u - 30);            // bottom row
        else { int v = u - 60; idx = ((v >> 1) + 1) * PPITCH + (v & 1) * 29; }
        planes[c12 * PPLANE + idx] = 0;
    }
    __syncthreads();

    // ---- phase C: conv. Lanes consecutive in y; bank stride 15 (odd). ----
    float acc[4][4] = {};   // [oc][px]
    const int y = tid % 28, xs = tid / 28, x0 = xs * 4;
    if (tid < 196) {
#pragma unroll 1   // CRITICAL: full unroll makes the scheduler hoist all 12
                   // channels' plane loads (~216 live floats) -> 256 VGPR + spill
        for (int c = 0; c < 12; ++c) {
            float rr[3][6];
#pragma unroll
            for (int dy = 0; dy < 3; ++dy) {
                const uint* row = (const uint*)&planes[c * PPLANE + (y + dy) * PPITCH + x0];
#pragma unroll
                for (int jp = 0; jp < 3; ++jp) {
                    uint w = row[jp];
                    float2 f = __bfloat1622float2(*(const __hip_bfloat162*)&w);
                    rr[dy][2 * jp]     = f.x;
                    rr[dy][2 * jp + 1] = f.y;
                }
            }
#pragma unroll
            for (int oc = 0; oc < 4; ++oc) {
                const float4* wr = reinterpret_cast<const float4*>(&w2s[oc][c][0]);
                float4 wa = wr[0], wb = wr[1], wc = wr[2];
                const float wk[9] = {wa.x, wa.y, wa.z, wa.w, wb.x, wb.y, wb.z, wb.w, wc.x};
#pragma unroll
                for (int ky = 0; ky < 3; ++ky)
#pragma unroll
                    for (int kx = 0; kx < 3; ++kx) {
                        float wv = wk[ky * 3 + kx];
#pragma unroll
                        for (int px = 0; px < 4; ++px)
                            acc[oc][px] += wv * rr[ky][px + kx];
                    }
            }
        }

        // ---- phase D: combine + store (att values ready since phase A) ----
        const float r2 = rate2[0];
        const int wi = (y >> 2) - 1, wj = xs - 1;
        const bool inter = (wi >= 0) & (wi < 5) & (wj >= 0) & (wj < 5);
#pragma unroll
        for (int oc = 0; oc < 4; ++oc) {
            float av = inter ? attbs[oc][wi * 5 + wj] : 0.f;
            float4 o;
            o.x = av + r2 * acc[oc][0];
            o.y = av + r2 * acc[oc][1];
            o.z = av + r2 * acc[oc][2];
            o.w = av + r2 * acc[oc][3];
            *reinterpret_cast<float4*>(
                &out[((size_t)(b * 256 + 4 * g + oc)) * HWH + y * 28 + x0]) = o;
        }
    }
}

// ---------------------------------------------------------------------------
extern "C" void kernel_launch(void* const* d_in, const int* in_sizes, int n_in,
                              void* d_out, int out_size, void* d_ws, size_t ws_size,
                              hipStream_t stream) {
    const float* x     = (const float*)d_in[0];
    const float* w1    = (const float*)d_in[1];
    const float* b1    = (const float*)d_in[2];
    const float* w2    = (const float*)d_in[3];
    const float* b2    = (const float*)d_in[4];
    const float* w3    = (const float*)d_in[5];
    const float* b3    = (const float*)d_in[6];
    const float* fc_w  = (const float*)d_in[7];
    const float* dep_w = (const float*)d_in[8];
    // d_in[9]/d_in[10] = rel_height/rel_width: provably dead (mask collapse)
    const float* rate1 = (const float*)d_in[11];
    const float* rate2 = (const float*)d_in[12];
    float* out = (float*)d_out;

    // workspace layout (bytes):
    //   perm    [0, 88473600)          64*64*12*900*2 (PADDED planes)
    //   xT      [88473600, 114163712)  64*784*256*2
    //   attm    = xT base (reused AFTER gemm consumes xT; stream-ordered)
    //   wbf     [114163712, 114556928) 768*256*2
    //   W2      [114556928, 114667520) 256*108*4
    //   biascat [114667520, 114670592) 768*4
    char* wsb = (char*)d_ws;
    bf16*  perm    = (bf16*)wsb;
    bf16*  xT      = (bf16*)(wsb + 88473600);
    float* attm    = (float*)(wsb + 88473600);           // alias of xT
    bf16*  wbf     = (bf16*)(wsb + 114163712);
    float* W2      = (float*)(wsb + 114556928);
    float* biascat = (float*)(wsb + 114667520);

    fold_w2   <<<dim3(108),        dim3(256), 0, stream>>>(fc_w, dep_w, b1, b2, b3, W2, biascat);
    wprep     <<<dim3(768),        dim3(256), 0, stream>>>(w1, w2, w3, wbf);
    xpose     <<<dim3(25, 8, 64),  dim3(256), 0, stream>>>(x, xT);
    gemm_mfma <<<dim3(13, 3, 64),  dim3(256), 0, stream>>>(wbf, biascat, xT, perm);
    attmean   <<<dim3(64, 64),     dim3(256), 0, stream>>>(perm, rate1, attm);
    out_fused5<<<dim3(64, 64),     dim3(256), 0, stream>>>(perm, W2, attm, rate2, out);
}

// Round 6
// 249.730 us; speedup vs baseline: 1.0991x; 1.0591x over previous
//
#include <hip/hip_runtime.h>
#include <hip/hip_bf16.h>

typedef __hip_bfloat16 bf16;
typedef unsigned int uint;
typedef unsigned short ushort;

using frag8 = __attribute__((ext_vector_type(8))) short;   // 8 bf16
using f32x4 = __attribute__((ext_vector_type(4))) float;

#define HWH 784     // 28*28
#define PPITCH 30   // padded plane pitch (shorts)
#define PPLANE 900  // 30*30 shorts per plane
#define PBLK 10800  // 12*900 shorts per (b,g)

// ---------------------------------------------------------------------------
// Fold fc_w (9x12) into dep_w (256,9,3,3):  W2[oc][c12][k9]; also biascat.
// ---------------------------------------------------------------------------
__global__ __launch_bounds__(256) void fold_w2(const float* __restrict__ fc_w,
                                               const float* __restrict__ dep_w,
                                               const float* __restrict__ b1,
                                               const float* __restrict__ b2,
                                               const float* __restrict__ b3,
                                               float* __restrict__ W2,
                                               float* __restrict__ biascat) {
    int idx = blockIdx.x * 256 + threadIdx.x;   // oc*108 + c12*9 + k9
    if (idx < 768) {
        const float* bs = idx < 256 ? b1 : (idx < 512 ? b2 : b3);
        biascat[idx] = bs[idx & 255];
    }
    if (idx >= 256 * 108) return;
    int oc  = idx / 108;
    int r   = idx % 108;
    int c12 = r / 9;
    int k9  = r % 9;
    float s = 0.f;
#pragma unroll
    for (int o = 0; o < 9; ++o)
        s += fc_w[o * 12 + c12] * dep_w[oc * 81 + o * 9 + k9];
    W2[idx] = s;
}

// ---------------------------------------------------------------------------
// Weights f32 -> bf16, concatenated [768][256] (q:w1, k:w2, v:w3)
// ---------------------------------------------------------------------------
__global__ __launch_bounds__(256) void wprep(const float* __restrict__ w1,
                                             const float* __restrict__ w2,
                                             const float* __restrict__ w3,
                                             bf16* __restrict__ wbf) {
    int row = blockIdx.x, tid = threadIdx.x;
    const float* src = row < 256 ? w1 : (row < 512 ? w2 : w3);
    wbf[row * 256 + tid] = __float2bfloat16(src[(row & 255) * 256 + tid]);
}

// ---------------------------------------------------------------------------
// x [b][c=256][n=784] f32  ->  xT [b][n=784][c=256] bf16  (32x32 LDS tiles)
// ---------------------------------------------------------------------------
__global__ __launch_bounds__(256) void xpose(const float* __restrict__ x,
                                             bf16* __restrict__ xT) {
    __shared__ float t[32][33];
    const int n0 = blockIdx.x * 32, c0 = blockIdx.y * 32, b = blockIdx.z;
    const int tid = threadIdx.x;
    const float* xb = x + (size_t)b * (256 * HWH);
#pragma unroll
    for (int e = tid; e < 1024; e += 256) {
        int r = e >> 5, col = e & 31;           // r: c-index, col: n-index
        int n = n0 + col;
        t[r][col] = (n < HWH) ? xb[(size_t)(c0 + r) * HWH + n] : 0.f;
    }
    __syncthreads();
#pragma unroll
    for (int e = tid; e < 512; e += 256) {
        int r = e >> 4, cp = (e & 15) * 2;      // r: n-index, cp: c-pair
        int n = n0 + r;
        if (n < HWH) {
            __hip_bfloat162 h;
            h.x = __float2bfloat16(t[cp][r]);
            h.y = __float2bfloat16(t[cp + 1][r]);
            *reinterpret_cast<__hip_bfloat162*>(
                &xT[((size_t)b * HWH + n) * 256 + c0 + cp]) = h;
        }
    }
}

// ---------------------------------------------------------------------------
// MFMA GEMM (R6): REVERT to the benched-best structure (73.7 us in R3 bench):
// 128x128 tile, 2x2 wave grid, 16 KB LDS, 2 barriers per K-step, grid 2688.
// History: single-barrier "B-once" restructures (R4: 86 us, R5: 83 us) traded
// barrier drains for exposed per-wave L2 latency on A-loads and LOST. Keep
// this structure.
// NEW in R6: XCD-aware block swizzle. Old grid (7n,6m,64b) put the 6 m-blocks
// sharing one B n-panel on 6 DIFFERENT XCDs (stride 7 over %8 round-robin) ->
// each XCD's L2 re-fetched the panel (FETCH 79 MB vs ~27 unique). Flat grid
// 2688, decode: X=s&7 (XCD), j=s>>3, G=X*56+j/6 (n,b group), mt=j%6.
// All 6 m-tiles of (n,b) -> same XCD, temporally adjacent -> 5/6 L2 hits.
// Bijective: 8 XCD x 56 groups = 448 = 7n x 64b.
// perm output: PADDED planes, image (y,x) at (y+1)*30+x+1; borders garbage.
// m -> sec=m/256, ch=m%256, g=ch%64, head=ch/64, t=sec*4+head.
// ---------------------------------------------------------------------------
__device__ inline void load_lds16(const bf16* g, short* lds) {
    __builtin_amdgcn_global_load_lds(
        (const __attribute__((address_space(1))) void*)g,
        (__attribute__((address_space(3))) void*)lds, 16, 0, 0);
}

__global__ __launch_bounds__(256) void gemm_mfma(const bf16* __restrict__ wbf,
                                                 const float* __restrict__ biascat,
                                                 const bf16* __restrict__ xT,
                                                 bf16* __restrict__ perm) {
    __shared__ short lds[8192];                 // A: [0,4096) shorts, B: [4096,8192)

    const int tid  = threadIdx.x;
    const int wave = tid >> 6, lane = tid & 63;

    // XCD-aware decode (see header comment)
    const int s  = blockIdx.x;
    const int X  = s & 7, j = s >> 3;
    const int G  = X * 56 + j / 6;              // (n,b) group in [0,448)
    const int mt = j % 6;
    const int nt = G % 7;
    const int b  = G / 7;

    const int m0   = mt * 128;
    const int n0   = nt * 128;
    const int mw   = wave & 1, nw = wave >> 1;  // 2x2 wave grid of 64x64 tiles
    const int lrow = lane & 15, lkc = lane >> 4;  // fragment row / k-chunk

    f32x4 acc[4][4] = {};
    const bf16* xb = xT + (size_t)b * (HWH * 256);

    for (int k0 = 0; k0 < 256; k0 += 32) {
#pragma unroll
        for (int i = 0; i < 2; ++i) {
            const int jb = 2 * wave + i;        // fragment-block (16 rows)
            const bf16* ga = wbf + (size_t)(m0 + 16 * jb + lrow) * 256 + k0 + lkc * 8;
            load_lds16(ga, &lds[jb * 512]);
            int n = n0 + 16 * jb + lrow;
            if (n > HWH - 1) n = HWH - 1;       // clamp: OOB cols never stored
            const bf16* gb = xb + (size_t)n * 256 + k0 + lkc * 8;
            load_lds16(gb, &lds[4096 + jb * 512]);
        }
        __syncthreads();

        frag8 af[4], bf_[4];
#pragma unroll
        for (int i = 0; i < 4; ++i)
            af[i] = *reinterpret_cast<const frag8*>(&lds[(4 * mw + i) * 512 + lane * 8]);
#pragma unroll
        for (int j2 = 0; j2 < 4; ++j2)
            bf_[j2] = *reinterpret_cast<const frag8*>(&lds[4096 + (4 * nw + j2) * 512 + lane * 8]);
#pragma unroll
        for (int i = 0; i < 4; ++i)
#pragma unroll
            for (int j2 = 0; j2 < 4; ++j2)
                acc[i][j2] = __builtin_amdgcn_mfma_f32_16x16x32_bf16(
                    af[i], bf_[j2], acc[i][j2], 0, 0, 0);
        __syncthreads();
    }

    // Epilogue: C/D layout col=lane&15 (n), row=(lane>>4)*4+reg (m)
    // Store into padded plane position (y+1)*30 + (x+1) = col + 2*(col/28) + 31
#pragma unroll
    for (int i = 0; i < 4; ++i) {
        const int rowb = m0 + mw * 64 + i * 16 + lkc * 4;
        bf16* base[4]; float bias4[4];
#pragma unroll
        for (int r = 0; r < 4; ++r) {
            const int m = rowb + r;
            const int sec = m >> 8, ch = m & 255;
            base[r] = perm + ((size_t)b * 64 + (ch & 63)) * PBLK
                           + (size_t)(sec * 4 + (ch >> 6)) * PPLANE;
            bias4[r] = biascat[m];
        }
#pragma unroll
        for (int j2 = 0; j2 < 4; ++j2) {
            const int col = n0 + nw * 64 + j2 * 16 + lrow;
            if (col < HWH) {
                const int pos = col + 2 * (col / 28) + 31;
#pragma unroll
                for (int r = 0; r < 4; ++r)
                    base[r][pos] = __float2bfloat16(acc[i][j2][r] + bias4[r]);
            }
        }
    }
}

// ---------------------------------------------------------------------------
// attmean: interior 12x12 window means of v, prescaled by rate1/144.
// attm[b][c][25] f32. One wave per channel; lanes 0..27 own columns.
// v channel c lives at perm[b][c&63][8 + c/64] (bias already included).
// ---------------------------------------------------------------------------
__global__ __launch_bounds__(256) void attmean(const bf16* __restrict__ perm,
                                               const float* __restrict__ rate1,
                                               float* __restrict__ attm) {
    const int b = blockIdx.y, cg = blockIdx.x;            // cg in [0,64)
    const int wave = threadIdx.x >> 6, lane = threadIdx.x & 63;
    const int c = cg * 4 + wave;                          // channel 0..255
    const bf16* vp = perm + ((size_t)(b * 64 + (c & 63)) * 12 + 8 + (c >> 6)) * (size_t)PPLANE;

    float cs[5] = {0.f, 0.f, 0.f, 0.f, 0.f};              // per-wi column sums
    if (lane < 28) {
#pragma unroll
        for (int y = 0; y < 28; ++y) {
            float v = __bfloat162float(vp[(y + 1) * PPITCH + lane + 1]);
#pragma unroll
            for (int wi = 0; wi < 5; ++wi)
                if (y >= 4 * wi && y <= 4 * wi + 11) cs[wi] += v;
        }
    }
    const float r1s = rate1[0] * (1.0f / 144.0f);
#pragma unroll
    for (int wi = 0; wi < 5; ++wi) {
        float p = cs[wi];
#pragma unroll
        for (int d = 1; d < 32; d <<= 1) {                // inclusive prefix over lanes
            float t = __shfl_up(p, d);
            if (lane >= d) p += t;
        }
        float hi = __shfl(p, 4 * lane + 11);              // valid for lane<5
        float lo = __shfl(p, 4 * lane - 1);
        if (lane < 5) {
            float w = hi - (lane ? lo : 0.f);
            attm[((size_t)b * 256 + c) * 25 + wi * 5 + lane] = w * r1s;
        }
    }
}

// ---------------------------------------------------------------------------
// out_fused5: out = att(precomputed means) + rate2 * conv.
// Phase A: straight uint4 copy of 12 padded planes (21.6 KB) + weights + att.
// Phase A2: zero halo borders in LDS (116 shorts/plane).
// Phase C: 3x3 conv, 196 threads x 4 oc x 4 px, pitch 30 (bank stride 15).
// LDS ~24.3 KB -> 6 blocks/CU by LDS.
// VGPR history: (256,6) clamp -> 40 VGPR, spill catastrophe (R1).
//               plain bounds + full c-unroll -> 256 VGPR, compiler hoisted
//               12 channels of rr loads (~216 live floats), spilled anyway (R2).
// Fix: #pragma unroll 1 on the channel loop — bounds live set to ~60 floats
// (one channel's rr[3][6] + acc[4][4] + transient wk). DO NOT re-unroll.
// ---------------------------------------------------------------------------
__global__ __launch_bounds__(256) void out_fused5(
    const bf16* __restrict__ perm, const float* __restrict__ W2,
    const float* __restrict__ attm, const float* __restrict__ rate2,
    float* __restrict__ out) {
    __shared__ __align__(16) short planes[12 * PPLANE];   // 21600 B, linear
    __shared__ float w2s[4][12][12];                      // [oc][c][k], k 9->12
    __shared__ float attbs[4][25];

    const int g = blockIdx.x, b = blockIdx.y, tid = threadIdx.x;

    // ---- phase A: linear LDS fill ----
    const uint4* src = (const uint4*)(perm + (size_t)(b * 64 + g) * PBLK);
#pragma unroll
    for (int it = 0; it < 6; ++it) {
        int e = tid + it * 256;                 // 1350 x 16B chunks
        if (e < 1350) ((uint4*)planes)[e] = src[e];
    }
    for (int e = tid; e < 576; e += 256) {
        int oc = e / 144, rem = e % 144, cc = rem / 12, k = rem % 12;
        w2s[oc][cc][k] = (k < 9) ? W2[(4 * g + oc) * 108 + cc * 9 + k] : 0.f;
    }
    if (tid < 100)
        attbs[tid / 25][tid % 25] =
            attm[((size_t)b * 256 + 4 * g + tid / 25) * 25 + tid % 25];
    __syncthreads();

    // ---- phase A2: zero halo borders (global borders hold garbage) ----
    for (int e = tid; e < 1392; e += 256) {
        int c12 = e / 116, u = e % 116, idx;
        if (u < 30)      idx = u;                         // top row
        else if (u < 60) idx = 870 + (u - 30);            // bottom row
        else { int v = u - 60; idx = ((v >> 1) + 1) * PPITCH + (v & 1) * 29; }
        planes[c12 * PPLANE + idx] = 0;
    }
    __syncthreads();

    // ---- phase C: conv. Lanes consecutive in y; bank stride 15 (odd). ----
    float acc[4][4] = {};   // [oc][px]
    const int y = tid % 28, xs = tid / 28, x0 = xs * 4;
    if (tid < 196) {
#pragma unroll 1   // CRITICAL: full unroll makes the scheduler hoist all 12
                   // channels' plane loads (~216 live floats) -> 256 VGPR + spill
        for (int c = 0; c < 12; ++c) {
            float rr[3][6];
#pragma unroll
            for (int dy = 0; dy < 3; ++dy) {
                const uint* row = (const uint*)&planes[c * PPLANE + (y + dy) * PPITCH + x0];
#pragma unroll
                for (int jp = 0; jp < 3; ++jp) {
                    uint w = row[jp];
                    float2 f = __bfloat1622float2(*(const __hip_bfloat162*)&w);
                    rr[dy][2 * jp]     = f.x;
                    rr[dy][2 * jp + 1] = f.y;
                }
            }
#pragma unroll
            for (int oc = 0; oc < 4; ++oc) {
                const float4* wr = reinterpret_cast<const float4*>(&w2s[oc][c][0]);
                float4 wa = wr[0], wb = wr[1], wc = wr[2];
                const float wk[9] = {wa.x, wa.y, wa.z, wa.w, wb.x, wb.y, wb.z, wb.w, wc.x};
#pragma unroll
                for (int ky = 0; ky < 3; ++ky)
#pragma unroll
                    for (int kx = 0; kx < 3; ++kx) {
                        float wv = wk[ky * 3 + kx];
#pragma unroll
                        for (int px = 0; px < 4; ++px)
                            acc[oc][px] += wv * rr[ky][px + kx];
                    }
            }
        }

        // ---- phase D: combine + store (att values ready since phase A) ----
        const float r2 = rate2[0];
        const int wi = (y >> 2) - 1, wj = xs - 1;
        const bool inter = (wi >= 0) & (wi < 5) & (wj >= 0) & (wj < 5);
#pragma unroll
        for (int oc = 0; oc < 4; ++oc) {
            float av = inter ? attbs[oc][wi * 5 + wj] : 0.f;
            float4 o;
            o.x = av + r2 * acc[oc][0];
            o.y = av + r2 * acc[oc][1];
            o.z = av + r2 * acc[oc][2];
            o.w = av + r2 * acc[oc][3];
            *reinterpret_cast<float4*>(
                &out[((size_t)(b * 256 + 4 * g + oc)) * HWH + y * 28 + x0]) = o;
        }
    }
}

// ---------------------------------------------------------------------------
extern "C" void kernel_launch(void* const* d_in, const int* in_sizes, int n_in,
                              void* d_out, int out_size, void* d_ws, size_t ws_size,
                              hipStream_t stream) {
    const float* x     = (const float*)d_in[0];
    const float* w1    = (const float*)d_in[1];
    const float* b1    = (const float*)d_in[2];
    const float* w2    = (const float*)d_in[3];
    const float* b2    = (const float*)d_in[4];
    const float* w3    = (const float*)d_in[5];
    const float* b3    = (const float*)d_in[6];
    const float* fc_w  = (const float*)d_in[7];
    const float* dep_w = (const float*)d_in[8];
    // d_in[9]/d_in[10] = rel_height/rel_width: provably dead (mask collapse)
    const float* rate1 = (const float*)d_in[11];
    const float* rate2 = (const float*)d_in[12];
    float* out = (float*)d_out;

    // workspace layout (bytes):
    //   perm    [0, 88473600)          64*64*12*900*2 (PADDED planes)
    //   xT      [88473600, 114163712)  64*784*256*2
    //   attm    = xT base (reused AFTER gemm consumes xT; stream-ordered)
    //   wbf     [114163712, 114556928) 768*256*2
    //   W2      [114556928, 114667520) 256*108*4
    //   biascat [114667520, 114670592) 768*4
    char* wsb = (char*)d_ws;
    bf16*  perm    = (bf16*)wsb;
    bf16*  xT      = (bf16*)(wsb + 88473600);
    float* attm    = (float*)(wsb + 88473600);           // alias of xT
    bf16*  wbf     = (bf16*)(wsb + 114163712);
    float* W2      = (float*)(wsb + 114556928);
    float* biascat = (float*)(wsb + 114667520);

    fold_w2   <<<dim3(108),        dim3(256), 0, stream>>>(fc_w, dep_w, b1, b2, b3, W2, biascat);
    wprep     <<<dim3(768),        dim3(256), 0, stream>>>(w1, w2, w3, wbf);
    xpose     <<<dim3(25, 8, 64),  dim3(256), 0, stream>>>(x, xT);
    gemm_mfma <<<dim3(2688),       dim3(256), 0, stream>>>(wbf, biascat, xT, perm);
    attmean   <<<dim3(64, 64),     dim3(256), 0, stream>>>(perm, rate1, attm);
    out_fused5<<<dim3(64, 64),     dim3(256), 0, stream>>>(perm, W2, attm, rate2, out);
}